// Round 4
// baseline (41.526 us; speedup 1.0000x reference)
//
#include <hip/hip_runtime.h>
#include <math.h>

#define NN 8192
#define NMODES 16
#define NB 32
#define NCH 64
#define NROWS (NB * NCH)       // 2048
#define TPB 256

#define K8 0.70710678118654752440f   // cos/sin(2*pi/8)

typedef float f32x4 __attribute__((ext_vector_type(4)));

// fine-rotation constants e^{i 2*pi*k*c/8192}, k=0..15, c=0..3 (tiny angles,
// constexpr Taylor — exact to ~1e-16 rel at max angle 0.0345 rad)
struct KCTab { float c[16][4]; float s[16][4]; };
constexpr KCTab make_kc() {
  KCTab r{};
  for (int k = 0; k < 16; ++k)
    for (int c = 0; c < 4; ++c) {
      double th = 6.283185307179586476925287 * (double)(k * c) / 8192.0;
      double x2 = th * th;
      r.c[k][c] = (float)(1.0 - x2 / 2.0 + x2 * x2 / 24.0 - x2 * x2 * x2 / 720.0);
      r.s[k][c] = (float)(th - th * x2 / 6.0 + th * x2 * x2 / 120.0 - th * x2 * x2 * x2 / 5040.0);
    }
  return r;
}
constexpr KCTab KCT = make_kc();

// Stage A: partial forward DFT, one block per (b, cin) row.
// n = 4t + 1024j + c. The j-sum against 8th roots IS a real 8-point DFT:
// compute it with a radix-2 network (22 ops/c, conj symmetry gives classes
// 5..7 free) instead of 80 ops/c of naive accumulation. 16-mode expansion,
// per-thread rotation, and distributed halving reduce as in R3 (verified).
__global__ __launch_bounds__(TPB) void fwd_dft_kernel(
    const float* __restrict__ v, float* __restrict__ vfpart) {
  const int row = blockIdx.x;
  const int t = threadIdx.x;
  const f32x4* __restrict__ vr4 = (const f32x4*)(v + (size_t)row * NN);

  // load 32 elements: x[c][j], n = 4t + 1024j + c
  float x[4][8];
#pragma unroll
  for (int j = 0; j < 8; ++j) {
    const f32x4 q = __builtin_nontemporal_load(vr4 + t + TPB * j);
    x[0][j] = q.x; x[1][j] = q.y; x[2][j] = q.z; x[3][j] = q.w;
  }

  // per-c real 8-point DFT, omega = e^{-2*pi*i/8}; X5..X7 = conj(X3..X1)
  float X0[4], X4[4], X1r[4], X1i[4], X2r[4], X2i[4], X3r[4], X3i[4];
#pragma unroll
  for (int c = 0; c < 4; ++c) {
    const float a  = x[c][0] + x[c][4], b = x[c][0] - x[c][4];
    const float cc = x[c][2] + x[c][6], d = x[c][2] - x[c][6];
    const float e  = x[c][1] + x[c][5], f = x[c][1] - x[c][5];
    const float g  = x[c][3] + x[c][7], h = x[c][3] - x[c][7];
    const float t1 = a + cc, t2 = e + g;
    X0[c]  = t1 + t2;
    X4[c]  = t1 - t2;
    X2r[c] = a - cc;  X2i[c] = g - e;
    const float u = K8 * (f - h), w = K8 * (f + h);
    X1r[c] = b + u;   X1i[c] = -d - w;
    X3r[c] = b - u;   X3i[c] = d - w;
  }

  // per-thread base rotation e^{-i 2*pi*4t*k/8192}: one double sincos
  double phi = (double)t * (6.283185307179586476925287 / 2048.0);
  double spd, cpd;
  sincos(phi, &spd, &cpd);
  const float c1 = (float)cpd, s1 = (float)spd;

  float pr[NMODES], pi[NMODES];
  float ck = 1.f, sk = 0.f;   // (cos k*phi, sin k*phi)
#pragma unroll
  for (int k = 0; k < NMODES; ++k) {
    const int m = k & 7;
    // gather class-m values (compile-time switch; conj for m>=5), then
    // combine c-slots with fine rotation e^{-i 2*pi*k*c/8192}
    float ar = 0.f, ai = 0.f;
#pragma unroll
    for (int c = 0; c < 4; ++c) {
      float br, bi;
      switch (m) {
        case 0:  br = X0[c];  bi = 0.f;      break;
        case 1:  br = X1r[c]; bi = X1i[c];   break;
        case 2:  br = X2r[c]; bi = X2i[c];   break;
        case 3:  br = X3r[c]; bi = X3i[c];   break;
        case 4:  br = X4[c];  bi = 0.f;      break;
        case 5:  br = X3r[c]; bi = -X3i[c];  break;
        case 6:  br = X2r[c]; bi = -X2i[c];  break;
        default: br = X1r[c]; bi = -X1i[c];  break;
      }
      if (c == 0) { ar = br; ai = bi; }
      else {
        ar = fmaf(br, KCT.c[k][c], fmaf(bi,  KCT.s[k][c], ar));
        ai = fmaf(bi, KCT.c[k][c], fmaf(br, -KCT.s[k][c], ai));
      }
    }
    // rotate by e^{-i k phi}
    pr[k] = ar * ck + ai * sk;
    pi[k] = ai * ck - ar * sk;
    const float cn = ck * c1 - sk * s1;
    const float sn = sk * c1 + ck * s1;
    ck = cn; sk = sn;
  }

  // distributed reduce: slot s (0..31) = [pr[0..15], pi[0..15]];
  // at xor-level d, keep slots with (s&d)==(lane&d) -> final slot = lane&31
  const int lane = t & 63, wave = t >> 6;

  float u16[16];
  {
    const bool hi = (lane & 16) != 0;
#pragma unroll
    for (int i = 0; i < 16; ++i) {
      const float send = hi ? pr[i] : pi[i];
      const float recv = __shfl_xor(send, 16);
      u16[i] = (hi ? pi[i] : pr[i]) + recv;
    }
  }
  float u8[8];
  {
    const bool hi = (lane & 8) != 0;
#pragma unroll
    for (int i = 0; i < 8; ++i) {
      const float send = hi ? u16[i] : u16[i + 8];
      const float recv = __shfl_xor(send, 8);
      u8[i] = (hi ? u16[i + 8] : u16[i]) + recv;
    }
  }
  float u4[4];
  {
    const bool hi = (lane & 4) != 0;
#pragma unroll
    for (int i = 0; i < 4; ++i) {
      const float send = hi ? u8[i] : u8[i + 4];
      const float recv = __shfl_xor(send, 4);
      u4[i] = (hi ? u8[i + 4] : u8[i]) + recv;
    }
  }
  float u2[2];
  {
    const bool hi = (lane & 2) != 0;
#pragma unroll
    for (int i = 0; i < 2; ++i) {
      const float send = hi ? u2[i] * 0.f + (hi ? u4[i] : u4[i + 2]) : u4[i + 2];
      (void)send;
      const float s2 = hi ? u4[i] : u4[i + 2];
      const float recv = __shfl_xor(s2, 2);
      u2[i] = (hi ? u4[i + 2] : u4[i]) + recv;
    }
  }
  float u1;
  {
    const bool hi = (lane & 1) != 0;
    const float send = hi ? u2[0] : u2[1];
    const float recv = __shfl_xor(send, 1);
    u1 = (hi ? u2[1] : u2[0]) + recv;
  }
  const float total = u1 + __shfl_xor(u1, 32);

  if (lane < 32) {
    // planar layout: part[w*32 + s], s<16: Re(mode s), s>=16: Im(mode s-16)
    vfpart[((size_t)row * 4 + wave) * 32 + lane] = total;
  }
}

// Stage B: fused {sum wave partials + channel mix} prologue, then inverse
// synthesis. E[m] (the k,k+8 fold) is built on the fly; the 8-point
// synthesis per c-slot runs as Hermitian fold + C2R butterfly (28 ops/c
// instead of 80).
__global__ __launch_bounds__(TPB) void mix_inv_kernel(
    const float* __restrict__ vfpart, const float* __restrict__ wre,
    const float* __restrict__ wim, float* __restrict__ out) {
  const int bid = blockIdx.x;
  const int b = bid >> 6, o = bid & 63;
  const int t = threadIdx.x;

  __shared__ float red[16][33];
  __shared__ float lvs[32];

  // ---- mix: lv[k] = sum_i W[k,o,i] * vf[b,i,k] (also sums 4 wave partials)
  {
    const int k = t & 15, g = t >> 4;
    float lr = 0.f, li = 0.f;
#pragma unroll
    for (int ii = 0; ii < 4; ++ii) {
      const int i = g * 4 + ii;
      const float* __restrict__ p = vfpart + (size_t)(b * NCH + i) * 128;
      float vr = 0.f, vi = 0.f;
#pragma unroll
      for (int w = 0; w < 4; ++w) {
        vr += p[w * 32 + k];
        vi += p[w * 32 + 16 + k];
      }
      const float wr = wre[((size_t)k * NCH + o) * NCH + i];
      const float wi = wim[((size_t)k * NCH + o) * NCH + i];
      lr = fmaf(wr, vr, fmaf(-wi, vi, lr));
      li = fmaf(wr, vi, fmaf( wi, vr, li));
    }
    red[g][k]      = lr;
    red[g][16 + k] = li;
  }
  __syncthreads();
  if (t < 32) {
    float s = 0.f;
#pragma unroll
    for (int g = 0; g < 16; ++g) s += red[g][t];
    const float gk = ((t & 15) == 0) ? (1.0f / (float)NN) : (2.0f / (float)NN);
    lvs[t] = s * gk;   // lvs[k]=re, lvs[16+k]=im, scaled A_k
  }
  __syncthreads();

  // ---- build E_c[m] = sum over {k: k&7==m} of A_k e^{+i k phi} e^{+i 2pi k c/8192}
  double phi = (double)t * (6.283185307179586476925287 / 2048.0);
  double spd, cpd;
  sincos(phi, &spd, &cpd);
  const float c1 = (float)cpd, s1 = (float)spd;

  float Er[4][8], Ei[4][8];
  {
    float ck = 1.f, sk = 0.f;
#pragma unroll
    for (int k = 0; k < NMODES; ++k) {
      const int m = k & 7;
      const float Ar = lvs[k], Ai = lvs[16 + k];
      const float xr = Ar * ck - Ai * sk;   // A_k * e^{+i k phi}
      const float xi = Ai * ck + Ar * sk;
      if (k < 8) { Er[0][m] = xr; Ei[0][m] = xi; }
      else       { Er[0][m] += xr; Ei[0][m] += xi; }
#pragma unroll
      for (int c = 1; c < 4; ++c) {
        const float dr = fmaf(xr, KCT.c[k][c], -xi * KCT.s[k][c]);
        const float di = fmaf(xi, KCT.c[k][c],  xr * KCT.s[k][c]);
        if (k < 8) { Er[c][m] = dr; Ei[c][m] = di; }
        else       { Er[c][m] += dr; Ei[c][m] += di; }
      }
      const float cn = ck * c1 - sk * s1;
      const float sn = sk * c1 + ck * s1;
      ck = cn; sk = sn;
    }
  }

  // ---- per-c C2R 8-point synthesis:
  // y_j = Er0 + (-1)^j Er4 + sum_{m=1..3} [P_m cos(2pi m j/8) - Q_m sin(..)]
  float y[4][8];
#pragma unroll
  for (int c = 0; c < 4; ++c) {
    const float P0 = Er[c][0], P4 = Er[c][4];
    const float P1 = Er[c][1] + Er[c][7], Q1 = Ei[c][1] - Ei[c][7];
    const float P2 = Er[c][2] + Er[c][6], Q2 = Ei[c][2] - Ei[c][6];
    const float P3 = Er[c][3] + Er[c][5], Q3 = Ei[c][3] - Ei[c][5];
    const float s04 = P0 + P4, d04 = P0 - P4;
    const float e0 = s04 + P2, e2 = s04 - P2;
    const float e1 = d04 - Q2, e3 = d04 + Q2;
    const float alpha = P1 - P3, beta = Q1 + Q3;
    const float O0 = P1 + P3;
    const float O2 = Q3 - Q1;
    const float O1 =  K8 * (alpha - beta);
    const float O3 = -K8 * (alpha + beta);
    y[c][0] = e0 + O0; y[c][4] = e0 - O0;
    y[c][1] = e1 + O1; y[c][5] = e1 - O1;
    y[c][2] = e2 + O2; y[c][6] = e2 - O2;
    y[c][3] = e3 + O3; y[c][7] = e3 - O3;
  }

  f32x4* __restrict__ out4 = (f32x4*)(out + (size_t)bid * NN);
#pragma unroll
  for (int j = 0; j < 8; ++j) {
    f32x4 r;
    r.x = y[0][j]; r.y = y[1][j]; r.z = y[2][j]; r.w = y[3][j];
    __builtin_nontemporal_store(r, out4 + t + TPB * j);
  }
}

extern "C" void kernel_launch(void* const* d_in, const int* in_sizes, int n_in,
                              void* d_out, int out_size, void* d_ws, size_t ws_size,
                              hipStream_t stream) {
  const float* v   = (const float*)d_in[0];   // [32, 64, 8192]
  const float* wre = (const float*)d_in[1];   // [16, 64, 64]
  const float* wim = (const float*)d_in[2];   // [16, 64, 64]
  float* out = (float*)d_out;                 // [32, 64, 8192]

  float* vfpart = (float*)d_ws;               // 2048 * 4 * 32 floats = 1 MB

  fwd_dft_kernel<<<NROWS, TPB, 0, stream>>>(v, vfpart);
  mix_inv_kernel<<<NROWS, TPB, 0, stream>>>(vfpart, wre, wim, out);
}

// Round 5
// 31.878 us; speedup vs baseline: 1.3027x; 1.3027x over previous
//
#include <hip/hip_runtime.h>
#include <math.h>

#define NN 8192
#define NMODES 16
#define NB 32
#define NCH 64
#define NROWS (NB * NCH)       // 2048
#define TPB 256

#define K8 0.70710678118654752440f   // cos/sin(2*pi/8)

typedef float f32x4 __attribute__((ext_vector_type(4)));

// fine-rotation constants e^{i 2*pi*k*c/8192}, k=0..15, c=0..3 (tiny angles,
// constexpr Taylor — exact to ~1e-16 rel at max angle 0.0345 rad)
struct KCTab { float c[16][4]; float s[16][4]; };
constexpr KCTab make_kc() {
  KCTab r{};
  for (int k = 0; k < 16; ++k)
    for (int c = 0; c < 4; ++c) {
      double th = 6.283185307179586476925287 * (double)(k * c) / 8192.0;
      double x2 = th * th;
      r.c[k][c] = (float)(1.0 - x2 / 2.0 + x2 * x2 / 24.0 - x2 * x2 * x2 / 720.0);
      r.s[k][c] = (float)(th - th * x2 / 6.0 + th * x2 * x2 / 120.0 - th * x2 * x2 * x2 / 5040.0);
    }
  return r;
}
constexpr KCTab KCT = make_kc();

// Stage A: partial forward DFT, one block per (b, cin) row.
// n = 4t + 1024j + c. The j-sum against 8th roots IS a real 8-point DFT:
// radix-2 network (22 ops/c, conj symmetry gives classes 5..7 free).
// NOTE (R4 lesson): plain loads — nontemporal flags regressed ~8 us total.
__global__ __launch_bounds__(TPB) void fwd_dft_kernel(
    const float* __restrict__ v, float* __restrict__ vfpart) {
  const int row = blockIdx.x;
  const int t = threadIdx.x;
  const f32x4* __restrict__ vr4 = (const f32x4*)(v + (size_t)row * NN);

  // load 32 elements: x[c][j], n = 4t + 1024j + c
  float x[4][8];
#pragma unroll
  for (int j = 0; j < 8; ++j) {
    const f32x4 q = vr4[t + TPB * j];
    x[0][j] = q.x; x[1][j] = q.y; x[2][j] = q.z; x[3][j] = q.w;
  }

  // per-c real 8-point DFT, omega = e^{-2*pi*i/8}; X5..X7 = conj(X3..X1)
  float X0[4], X4[4], X1r[4], X1i[4], X2r[4], X2i[4], X3r[4], X3i[4];
#pragma unroll
  for (int c = 0; c < 4; ++c) {
    const float a  = x[c][0] + x[c][4], b = x[c][0] - x[c][4];
    const float cc = x[c][2] + x[c][6], d = x[c][2] - x[c][6];
    const float e  = x[c][1] + x[c][5], f = x[c][1] - x[c][5];
    const float g  = x[c][3] + x[c][7], h = x[c][3] - x[c][7];
    const float t1 = a + cc, t2 = e + g;
    X0[c]  = t1 + t2;
    X4[c]  = t1 - t2;
    X2r[c] = a - cc;  X2i[c] = g - e;
    const float u = K8 * (f - h), w = K8 * (f + h);
    X1r[c] = b + u;   X1i[c] = -d - w;
    X3r[c] = b - u;   X3i[c] = d - w;
  }

  // per-thread base rotation e^{-i 2*pi*4t*k/8192}: one double sincos
  double phi = (double)t * (6.283185307179586476925287 / 2048.0);
  double spd, cpd;
  sincos(phi, &spd, &cpd);
  const float c1 = (float)cpd, s1 = (float)spd;

  float pr[NMODES], pi[NMODES];
  float ck = 1.f, sk = 0.f;   // (cos k*phi, sin k*phi)
#pragma unroll
  for (int k = 0; k < NMODES; ++k) {
    const int m = k & 7;
    // gather class-m values (compile-time switch; conj for m>=5), then
    // combine c-slots with fine rotation e^{-i 2*pi*k*c/8192}
    float ar = 0.f, ai = 0.f;
#pragma unroll
    for (int c = 0; c < 4; ++c) {
      float br, bi;
      switch (m) {
        case 0:  br = X0[c];  bi = 0.f;      break;
        case 1:  br = X1r[c]; bi = X1i[c];   break;
        case 2:  br = X2r[c]; bi = X2i[c];   break;
        case 3:  br = X3r[c]; bi = X3i[c];   break;
        case 4:  br = X4[c];  bi = 0.f;      break;
        case 5:  br = X3r[c]; bi = -X3i[c];  break;
        case 6:  br = X2r[c]; bi = -X2i[c];  break;
        default: br = X1r[c]; bi = -X1i[c];  break;
      }
      if (c == 0) { ar = br; ai = bi; }
      else {
        ar = fmaf(br, KCT.c[k][c], fmaf(bi,  KCT.s[k][c], ar));
        ai = fmaf(bi, KCT.c[k][c], fmaf(br, -KCT.s[k][c], ai));
      }
    }
    // rotate by e^{-i k phi}
    pr[k] = ar * ck + ai * sk;
    pi[k] = ai * ck - ar * sk;
    const float cn = ck * c1 - sk * s1;
    const float sn = sk * c1 + ck * s1;
    ck = cn; sk = sn;
  }

  // distributed reduce: slot s (0..31) = [pr[0..15], pi[0..15]];
  // at xor-level d, keep slots with (s&d)==(lane&d) -> final slot = lane&31
  const int lane = t & 63, wave = t >> 6;

  float u16[16];
  {
    const bool hi = (lane & 16) != 0;
#pragma unroll
    for (int i = 0; i < 16; ++i) {
      const float send = hi ? pr[i] : pi[i];
      const float recv = __shfl_xor(send, 16);
      u16[i] = (hi ? pi[i] : pr[i]) + recv;
    }
  }
  float u8[8];
  {
    const bool hi = (lane & 8) != 0;
#pragma unroll
    for (int i = 0; i < 8; ++i) {
      const float send = hi ? u16[i] : u16[i + 8];
      const float recv = __shfl_xor(send, 8);
      u8[i] = (hi ? u16[i + 8] : u16[i]) + recv;
    }
  }
  float u4[4];
  {
    const bool hi = (lane & 4) != 0;
#pragma unroll
    for (int i = 0; i < 4; ++i) {
      const float send = hi ? u8[i] : u8[i + 4];
      const float recv = __shfl_xor(send, 4);
      u4[i] = (hi ? u8[i + 4] : u8[i]) + recv;
    }
  }
  float u2[2];
  {
    const bool hi = (lane & 2) != 0;
#pragma unroll
    for (int i = 0; i < 2; ++i) {
      const float send = hi ? u4[i] : u4[i + 2];
      const float recv = __shfl_xor(send, 2);
      u2[i] = (hi ? u4[i + 2] : u4[i]) + recv;
    }
  }
  float u1;
  {
    const bool hi = (lane & 1) != 0;
    const float send = hi ? u2[0] : u2[1];
    const float recv = __shfl_xor(send, 1);
    u1 = (hi ? u2[1] : u2[0]) + recv;
  }
  const float total = u1 + __shfl_xor(u1, 32);

  if (lane < 32) {
    // planar layout: part[w*32 + s], s<16: Re(mode s), s>=16: Im(mode s-16)
    vfpart[((size_t)row * 4 + wave) * 32 + lane] = total;
  }
}

// Stage B: fused {sum wave partials + channel mix} prologue, then inverse
// synthesis. E[m] (the k,k+8 fold) is built on the fly; the 8-point
// synthesis per c-slot runs as Hermitian fold + C2R butterfly (28 ops/c
// instead of 80). Plain stores (NT regressed in R4).
__global__ __launch_bounds__(TPB) void mix_inv_kernel(
    const float* __restrict__ vfpart, const float* __restrict__ wre,
    const float* __restrict__ wim, float* __restrict__ out) {
  const int bid = blockIdx.x;
  const int b = bid >> 6, o = bid & 63;
  const int t = threadIdx.x;

  __shared__ float red[16][33];
  __shared__ float lvs[32];

  // ---- mix: lv[k] = sum_i W[k,o,i] * vf[b,i,k] (also sums 4 wave partials)
  {
    const int k = t & 15, g = t >> 4;
    float lr = 0.f, li = 0.f;
#pragma unroll
    for (int ii = 0; ii < 4; ++ii) {
      const int i = g * 4 + ii;
      const float* __restrict__ p = vfpart + (size_t)(b * NCH + i) * 128;
      float vr = 0.f, vi = 0.f;
#pragma unroll
      for (int w = 0; w < 4; ++w) {
        vr += p[w * 32 + k];
        vi += p[w * 32 + 16 + k];
      }
      const float wr = wre[((size_t)k * NCH + o) * NCH + i];
      const float wi = wim[((size_t)k * NCH + o) * NCH + i];
      lr = fmaf(wr, vr, fmaf(-wi, vi, lr));
      li = fmaf(wr, vi, fmaf( wi, vr, li));
    }
    red[g][k]      = lr;
    red[g][16 + k] = li;
  }
  __syncthreads();
  if (t < 32) {
    float s = 0.f;
#pragma unroll
    for (int g = 0; g < 16; ++g) s += red[g][t];
    const float gk = ((t & 15) == 0) ? (1.0f / (float)NN) : (2.0f / (float)NN);
    lvs[t] = s * gk;   // lvs[k]=re, lvs[16+k]=im, scaled A_k
  }
  __syncthreads();

  // ---- build E_c[m] = sum over {k: k&7==m} of A_k e^{+i k phi} e^{+i 2pi k c/8192}
  double phi = (double)t * (6.283185307179586476925287 / 2048.0);
  double spd, cpd;
  sincos(phi, &spd, &cpd);
  const float c1 = (float)cpd, s1 = (float)spd;

  float Er[4][8], Ei[4][8];
  {
    float ck = 1.f, sk = 0.f;
#pragma unroll
    for (int k = 0; k < NMODES; ++k) {
      const int m = k & 7;
      const float Ar = lvs[k], Ai = lvs[16 + k];
      const float xr = Ar * ck - Ai * sk;   // A_k * e^{+i k phi}
      const float xi = Ai * ck + Ar * sk;
      if (k < 8) { Er[0][m] = xr; Ei[0][m] = xi; }
      else       { Er[0][m] += xr; Ei[0][m] += xi; }
#pragma unroll
      for (int c = 1; c < 4; ++c) {
        const float dr = fmaf(xr, KCT.c[k][c], -xi * KCT.s[k][c]);
        const float di = fmaf(xi, KCT.c[k][c],  xr * KCT.s[k][c]);
        if (k < 8) { Er[c][m] = dr; Ei[c][m] = di; }
        else       { Er[c][m] += dr; Ei[c][m] += di; }
      }
      const float cn = ck * c1 - sk * s1;
      const float sn = sk * c1 + ck * s1;
      ck = cn; sk = sn;
    }
  }

  // ---- per-c C2R 8-point synthesis:
  // y_j = Er0 + (-1)^j Er4 + sum_{m=1..3} [P_m cos(2pi m j/8) - Q_m sin(..)]
  float y[4][8];
#pragma unroll
  for (int c = 0; c < 4; ++c) {
    const float P0 = Er[c][0], P4 = Er[c][4];
    const float P1 = Er[c][1] + Er[c][7], Q1 = Ei[c][1] - Ei[c][7];
    const float P2 = Er[c][2] + Er[c][6], Q2 = Ei[c][2] - Ei[c][6];
    const float P3 = Er[c][3] + Er[c][5], Q3 = Ei[c][3] - Ei[c][5];
    const float s04 = P0 + P4, d04 = P0 - P4;
    const float e0 = s04 + P2, e2 = s04 - P2;
    const float e1 = d04 - Q2, e3 = d04 + Q2;
    const float alpha = P1 - P3, beta = Q1 + Q3;
    const float O0 = P1 + P3;
    const float O2 = Q3 - Q1;
    const float O1 =  K8 * (alpha - beta);
    const float O3 = -K8 * (alpha + beta);
    y[c][0] = e0 + O0; y[c][4] = e0 - O0;
    y[c][1] = e1 + O1; y[c][5] = e1 - O1;
    y[c][2] = e2 + O2; y[c][6] = e2 - O2;
    y[c][3] = e3 + O3; y[c][7] = e3 - O3;
  }

  f32x4* __restrict__ out4 = (f32x4*)(out + (size_t)bid * NN);
#pragma unroll
  for (int j = 0; j < 8; ++j) {
    f32x4 r;
    r.x = y[0][j]; r.y = y[1][j]; r.z = y[2][j]; r.w = y[3][j];
    out4[t + TPB * j] = r;
  }
}

extern "C" void kernel_launch(void* const* d_in, const int* in_sizes, int n_in,
                              void* d_out, int out_size, void* d_ws, size_t ws_size,
                              hipStream_t stream) {
  const float* v   = (const float*)d_in[0];   // [32, 64, 8192]
  const float* wre = (const float*)d_in[1];   // [16, 64, 64]
  const float* wim = (const float*)d_in[2];   // [16, 64, 64]
  float* out = (float*)d_out;                 // [32, 64, 8192]

  float* vfpart = (float*)d_ws;               // 2048 * 4 * 32 floats = 1 MB

  fwd_dft_kernel<<<NROWS, TPB, 0, stream>>>(v, vfpart);
  mix_inv_kernel<<<NROWS, TPB, 0, stream>>>(vfpart, wre, wim, out);
}